// Round 6
// baseline (50.289 us; speedup 1.0000x reference)
//
#include <hip/hip_runtime.h>

// MoE B=4096, D=256, H=1024, E=8. 3 launches:
//  K1 prep: blocks 0..511 W1->w1t[e][h][d] bf16; 512..1023 W2->w2t[e][d][h] bf16;
//           1024..1031 deterministic ballot/prefix bin (1 block per expert)
//  K2 gemm1: stage x directly via bucket (fp32->bf16), h = relu(x @ W1 + b1) -> hw bf16
//            grid 8e x 16tile x 8 h-pairs (2 chunks of 64 h per block)
//  K3 gemm2: out[token] = hw @ w2t^T + b2, grid 8e x 16tile x 4 d-chunks

#define D_DIM 256
#define H_DIM 1024
#define E_NUM 8
#define B_TOK 4096
#define CAP   1024

typedef __attribute__((ext_vector_type(8))) short short8;
typedef __attribute__((ext_vector_type(4))) float f32x4;
typedef unsigned short u16;
typedef unsigned int u32;
typedef unsigned long long u64;

// ws layout (bytes)
#define CNT_OFF    0
#define BUCKET_OFF 1024
#define W1T_OFF    (BUCKET_OFF + E_NUM*B_TOK*4)
#define W2T_OFF    (W1T_OFF + (size_t)E_NUM*H_DIM*D_DIM*2)
#define HW_OFF     (W2T_OFF + (size_t)E_NUM*D_DIM*H_DIM*2)

__device__ __forceinline__ u16 f2bf(float f) {
    u32 u = __builtin_bit_cast(u32, f);
    u = (u + 0x7fffu + ((u >> 16) & 1u)) >> 16;  // RNE
    return (u16)u;
}

// 64x64 fp32->bf16 transpose tile (256 threads, 1 internal sync)
__device__ __forceinline__ void trans64(const float* __restrict__ in,
                                        u16* __restrict__ outp,
                                        int R, int C, int rt, int ct,
                                        int tt, u16* tile) {
    #pragma unroll
    for (int it = 0; it < 4; ++it) {
        int r = it * 16 + (tt >> 4);
        int c4 = (tt & 15) * 4;
        float4 v = *(const float4*)(in + (size_t)(rt * 64 + r) * C + ct * 64 + c4);
        u64 pk = (u64)f2bf(v.x) | ((u64)f2bf(v.y) << 16)
               | ((u64)f2bf(v.z) << 32) | ((u64)f2bf(v.w) << 48);
        *(u64*)&tile[r * 68 + c4] = pk;
    }
    __syncthreads();
    #pragma unroll
    for (int it = 0; it < 2; ++it) {
        int oc = it * 32 + (tt >> 3);
        int r0 = (tt & 7) * 8;
        u32 p0 = tile[(r0 + 0) * 68 + oc] | ((u32)tile[(r0 + 1) * 68 + oc] << 16);
        u32 p1 = tile[(r0 + 2) * 68 + oc] | ((u32)tile[(r0 + 3) * 68 + oc] << 16);
        u32 p2 = tile[(r0 + 4) * 68 + oc] | ((u32)tile[(r0 + 5) * 68 + oc] << 16);
        u32 p3 = tile[(r0 + 6) * 68 + oc] | ((u32)tile[(r0 + 7) * 68 + oc] << 16);
        *(uint4*)(outp + (size_t)(ct * 64 + oc) * R + rt * 64 + r0) = uint4{p0, p1, p2, p3};
    }
}

// ---- K1: prep = W1 transpose | W2 transpose | bin ----
__global__ __launch_bounds__(256) void prep_kernel(
    const float* __restrict__ W1, const float* __restrict__ W2,
    const int* __restrict__ eidx,
    int* __restrict__ cnt, int* __restrict__ bucket,
    u16* __restrict__ w1t, u16* __restrict__ w2t)
{
    __shared__ u16 tile[64 * 68];
    const int b = blockIdx.x, tid = threadIdx.x;
    if (b < 512) {                       // W1 [256d][1024h] -> w1t [h][d]
        int e = b >> 6, tj = b & 63;
        trans64(W1 + (size_t)e * D_DIM * H_DIM, w1t + (size_t)e * H_DIM * D_DIM,
                D_DIM, H_DIM, tj >> 4, tj & 15, tid, tile);
    } else if (b < 1024) {               // W2 [1024h][256d] -> w2t [d][h]
        int e = (b - 512) >> 6, tj = (b - 512) & 63;
        trans64(W2 + (size_t)e * H_DIM * D_DIM, w2t + (size_t)e * D_DIM * H_DIM,
                H_DIM, D_DIM, tj >> 2, tj & 3, tid, tile);
    } else {                             // bin: block per expert, deterministic scan
        __shared__ int wsum[4];
        const int e = b - 1024;
        const int lane = tid & 63, wv = tid >> 6;
        int base = 0;
        #pragma unroll
        for (int c = 0; c < 16; ++c) {
            int t = c * 256 + tid;
            bool m = (eidx[t] == e);
            u64 bal = __ballot(m);
            int pfx = __popcll(bal & ((1ull << lane) - 1ull));
            if (lane == 0) wsum[wv] = __popcll(bal);
            __syncthreads();
            int wb = 0, total = 0;
            #pragma unroll
            for (int i = 0; i < 4; ++i) { if (i < wv) wb += wsum[i]; total += wsum[i]; }
            if (m) bucket[e * B_TOK + base + wb + pfx] = t;
            base += total;
            __syncthreads();
        }
        if (tid == 0) cnt[e] = base;
    }
}

// ---- K2: GEMM1 with inline x gather. M=64, N=2x64, K=256 ----
__global__ __launch_bounds__(256, 2) void gemm1_kernel(
    const float* __restrict__ x, const u16* __restrict__ w1t,
    const float* __restrict__ b1, const int* __restrict__ cnt,
    const int* __restrict__ bucket, u16* __restrict__ hw)
{
    __shared__ u16 xs[64 * 264];    // 33792 B
    __shared__ u16 w1s[64 * 264];   // 33792 B
    __shared__ u16 hs[64 * 72];     //  9216 B   (76.8 KB total -> 2 blocks/CU)

    const int b = blockIdx.x;
    const int e = b >> 7, t = (b >> 3) & 15, hp = b & 7;
    const int n = min(cnt[e], CAP);
    const int row0 = t * 64;
    if (row0 >= n) return;

    const int tid = threadIdx.x;
    const int w = tid >> 6, L = tid & 63, l15 = L & 15, l4 = L >> 4;
    const int wr = (w >> 1) * 32, wc = (w & 1) * 32;

    // ---- stage x tile directly from scattered token rows (fp32 -> bf16)
    {
        const int l16 = tid & 15;
        #pragma unroll
        for (int rr = 0; rr < 4; ++rr) {
            int row = rr * 16 + (tid >> 4);
            bool valid = (row0 + row) < n;
            int token = valid ? bucket[e * B_TOK + row0 + row] : 0;
            const float* src = x + (size_t)token * D_DIM + l16 * 4;
            #pragma unroll
            for (int i = 0; i < 4; ++i) {
                float4 v = valid ? *(const float4*)(src + i * 64)
                                 : float4{0.f, 0.f, 0.f, 0.f};
                u64 pk = (u64)f2bf(v.x) | ((u64)f2bf(v.y) << 16)
                       | ((u64)f2bf(v.z) << 32) | ((u64)f2bf(v.w) << 48);
                *(u64*)&xs[row * 264 + l16 * 4 + i * 64] = pk;
            }
        }
    }

    for (int j = 0; j < 2; ++j) {
        const int hch = hp * 2 + j;
        // ---- stage W1 chunk [64h][256d] bf16
        {
            const u16* gw = w1t + ((size_t)e * H_DIM + hch * 64) * D_DIM;
            int rr = tid >> 5, cc = (tid & 31) * 8;
            #pragma unroll
            for (int it = 0; it < 8; ++it) {
                int row = it * 8 + rr;
                *(short8*)&w1s[row * 264 + cc] = *(const short8*)&gw[(size_t)row * D_DIM + cc];
            }
        }
        __syncthreads();   // w1s (and xs, and prev-j hs readers) ready

        f32x4 acc[2][2];
        #pragma unroll
        for (int i = 0; i < 2; ++i)
            #pragma unroll
            for (int jj = 0; jj < 2; ++jj) acc[i][jj] = (f32x4){0.f, 0.f, 0.f, 0.f};

        #pragma unroll
        for (int k = 0; k < 8; ++k) {
            short8 a0 = *(const short8*)&xs[(wr + l15) * 264 + k * 32 + l4 * 8];
            short8 a1 = *(const short8*)&xs[(wr + 16 + l15) * 264 + k * 32 + l4 * 8];
            short8 b0 = *(const short8*)&w1s[(wc + l15) * 264 + k * 32 + l4 * 8];
            short8 b1v = *(const short8*)&w1s[(wc + 16 + l15) * 264 + k * 32 + l4 * 8];
            acc[0][0] = __builtin_amdgcn_mfma_f32_16x16x32_bf16(a0, b0, acc[0][0], 0, 0, 0);
            acc[0][1] = __builtin_amdgcn_mfma_f32_16x16x32_bf16(a0, b1v, acc[0][1], 0, 0, 0);
            acc[1][0] = __builtin_amdgcn_mfma_f32_16x16x32_bf16(a1, b0, acc[1][0], 0, 0, 0);
            acc[1][1] = __builtin_amdgcn_mfma_f32_16x16x32_bf16(a1, b1v, acc[1][1], 0, 0, 0);
        }

        #pragma unroll
        for (int mr = 0; mr < 2; ++mr)
            #pragma unroll
            for (int nc = 0; nc < 2; ++nc) {
                float bias = b1[e * H_DIM + hch * 64 + wc + nc * 16 + l15];
                #pragma unroll
                for (int jj = 0; jj < 4; ++jj) {
                    float v = acc[mr][nc][jj] + bias;
                    v = fmaxf(v, 0.f);
                    hs[(wr + mr * 16 + l4 * 4 + jj) * 72 + wc + nc * 16 + l15] = f2bf(v);
                }
            }
        __syncthreads();   // hs complete (implies all MFMA reads of w1s done)

        {
            u16* gh = hw + ((size_t)e * CAP + row0) * H_DIM + hch * 64;
            int rr8 = tid >> 3, off = (tid & 7) * 8;
            #pragma unroll
            for (int it = 0; it < 2; ++it) {
                int row = it * 32 + rr8;
                *(short8*)&gh[(size_t)row * H_DIM + off] = *(const short8*)&hs[row * 72 + off];
            }
        }
        // next j: w1s restage races nothing (hw store reads hs only);
        // the pre-MFMA sync of next j orders hs overwrite after these reads.
    }
}

// ---- K3: GEMM2  M=64,N=64,K=1024 (4 chunks) ----
__global__ __launch_bounds__(256, 2) void gemm2_kernel(
    const u16* __restrict__ hw, const u16* __restrict__ w2t,
    const float* __restrict__ b2, const int* __restrict__ cnt,
    const int* __restrict__ bucket, float* __restrict__ out)
{
    __shared__ u16 as_[64 * 264];
    __shared__ u16 bs[64 * 264];

    int b = blockIdx.x;
    int e = b >> 6, tile = (b >> 2) & 15, nch = b & 3;
    int n = min(cnt[e], CAP);
    if (tile * 64 >= n) return;

    int tid = threadIdx.x;
    int w = tid >> 6, L = tid & 63, l15 = L & 15, l4 = L >> 4;
    int wr = (w >> 1) * 32, wc = (w & 1) * 32;

    f32x4 acc[2][2];
    #pragma unroll
    for (int i = 0; i < 2; ++i)
        #pragma unroll
        for (int j = 0; j < 2; ++j) acc[i][j] = (f32x4){0.f, 0.f, 0.f, 0.f};

    const u16* ga = hw + ((size_t)e * CAP + tile * 64) * H_DIM;
    const u16* gb = w2t + ((size_t)e * D_DIM + nch * 64) * H_DIM;

    for (int kc = 0; kc < 4; ++kc) {
        __syncthreads();
        int rr = tid >> 5, cc = (tid & 31) * 8;
        #pragma unroll
        for (int it = 0; it < 8; ++it) {
            int row = it * 8 + rr;
            *(short8*)&as_[row * 264 + cc] = *(const short8*)&ga[(size_t)row * H_DIM + kc * 256 + cc];
            *(short8*)&bs[row * 264 + cc]  = *(const short8*)&gb[(size_t)row * H_DIM + kc * 256 + cc];
        }
        __syncthreads();
        #pragma unroll
        for (int k = 0; k < 8; ++k) {
            short8 a0 = *(const short8*)&as_[(wr + l15) * 264 + k * 32 + l4 * 8];
            short8 a1 = *(const short8*)&as_[(wr + 16 + l15) * 264 + k * 32 + l4 * 8];
            short8 b0 = *(const short8*)&bs[(wc + l15) * 264 + k * 32 + l4 * 8];
            short8 b1v = *(const short8*)&bs[(wc + 16 + l15) * 264 + k * 32 + l4 * 8];
            acc[0][0] = __builtin_amdgcn_mfma_f32_16x16x32_bf16(a0, b0, acc[0][0], 0, 0, 0);
            acc[0][1] = __builtin_amdgcn_mfma_f32_16x16x32_bf16(a0, b1v, acc[0][1], 0, 0, 0);
            acc[1][0] = __builtin_amdgcn_mfma_f32_16x16x32_bf16(a1, b0, acc[1][0], 0, 0, 0);
            acc[1][1] = __builtin_amdgcn_mfma_f32_16x16x32_bf16(a1, b1v, acc[1][1], 0, 0, 0);
        }
    }

    #pragma unroll
    for (int mr = 0; mr < 2; ++mr)
        #pragma unroll
        for (int jj = 0; jj < 4; ++jj) {
            int m = wr + mr * 16 + l4 * 4 + jj;
            if (tile * 64 + m < n) {
                int token = bucket[e * B_TOK + tile * 64 + m];
                #pragma unroll
                for (int nc = 0; nc < 2; ++nc) {
                    int d = nch * 64 + wc + nc * 16 + l15;
                    out[(size_t)token * D_DIM + d] = acc[mr][nc][jj] + b2[e * D_DIM + d];
                }
            }
        }
}

extern "C" void kernel_launch(void* const* d_in, const int* in_sizes, int n_in,
                              void* d_out, int out_size, void* d_ws, size_t ws_size,
                              hipStream_t stream) {
    const float* x  = (const float*)d_in[0];
    const float* W1 = (const float*)d_in[1];
    const float* b1 = (const float*)d_in[2];
    const float* W2 = (const float*)d_in[3];
    const float* b2 = (const float*)d_in[4];
    const int* eidx = (const int*)d_in[5];
    float* out = (float*)d_out;

    char* ws = (char*)d_ws;
    int* cnt    = (int*)(ws + CNT_OFF);
    int* bucket = (int*)(ws + BUCKET_OFF);
    u16* w1t    = (u16*)(ws + W1T_OFF);
    u16* w2t    = (u16*)(ws + W2T_OFF);
    u16* hw     = (u16*)(ws + HW_OFF);

    prep_kernel<<<1032, 256, 0, stream>>>(W1, W2, eidx, cnt, bucket, w1t, w2t);
    gemm1_kernel<<<E_NUM * 16 * 8, 256, 0, stream>>>(x, w1t, b1, cnt, bucket, hw);
    gemm2_kernel<<<E_NUM * 16 * 4, 256, 0, stream>>>(hw, w2t, b2, cnt, bucket, out);
}